// Round 2
// baseline (980.092 us; speedup 1.0000x reference)
//
#include <hip/hip_runtime.h>
#include <stdint.h>

#define NB 128
#define NN 4096
#define NJ 256
#define NK 256
#define NITER 25

__device__ __forceinline__ float wredf(float v) {
#pragma unroll
  for (int o = 32; o > 0; o >>= 1) v += __shfl_xor(v, o, 64);
  return v;
}

// One block per batch, 256 threads.
__global__ __launch_bounds__(256) void km_main(
    const float* __restrict__ pts, const float* __restrict__ lg,
    const float* __restrict__ prob, float* __restrict__ kw,
    float* __restrict__ bloss) {
  const int b = blockIdx.x;
  const int t = threadIdx.x;
  const int lane = t & 63, wid = t >> 6;

  __shared__ unsigned long long keys[NN];      // 32 KB
  __shared__ int hist[4096];                   // 16 KB
  __shared__ int warr[4];
  __shared__ int ifind[2];
  __shared__ int cnt_sh;
  __shared__ int idxl[NK];
  __shared__ __align__(16) float x4[NK * 4];   // {x,y,z,0}
  __shared__ __align__(16) float mu4[NJ * 4];  // {mu, -10*log2e*|mu|^2}
  __shared__ float ckv[NK];                    // m + log Z (natural)
  __shared__ float cjv[NJ];                    // column marginal c_j
  __shared__ float av[NK];
  __shared__ __align__(16) float bv[NJ];
  __shared__ float redf4[4];

  // ---------- Phase A: exact top-256 (ties -> lower index) via radix select
  const float* pb = prob + (size_t)b * NN;
  for (int i = t; i < NN; i += 256) {
    unsigned bits = __float_as_uint(pb[i]);  // prob in [0,1): monotone bits
    keys[i] = ((unsigned long long)bits << 12) | (unsigned)(4095 - i);
  }
  unsigned long long theta = 0ull;
  int need = NK;
  const int shv[4] = {32, 20, 8, 0};
  const int psv[4] = {44, 32, 20, 8};
  __syncthreads();
#pragma unroll 1
  for (int L = 0; L < 4; ++L) {
    const int sh = shv[L], ps = psv[L];
    for (int i = t; i < 4096; i += 256) hist[i] = 0;
    __syncthreads();
    for (int i = t; i < NN; i += 256) {
      unsigned long long kk = keys[i];
      if ((kk >> ps) == (theta >> ps))
        atomicAdd(&hist[(int)((kk >> sh) & 0xFFFull)], 1);
    }
    __syncthreads();
    int loc[16];
    int tot = 0;
#pragma unroll
    for (int q = 15; q >= 0; --q) { loc[q] = tot; tot += hist[16 * t + q]; }
    int s = tot;  // inclusive suffix within wave
#pragma unroll
    for (int o = 1; o < 64; o <<= 1) {
      int u = __shfl_down(s, o, 64);
      if (lane + o < 64) s += u;
    }
    if (lane == 0) warr[wid] = s;
    __syncthreads();
    int gtw = s - tot;
    for (int w = wid + 1; w < 4; ++w) gtw += warr[w];
#pragma unroll
    for (int q = 0; q < 16; ++q) {
      int g = gtw + loc[q];
      int h = hist[16 * t + q];
      if (g < need && g + h >= need) { ifind[0] = 16 * t + q; ifind[1] = g; }
    }
    __syncthreads();
    theta |= ((unsigned long long)ifind[0]) << sh;
    need -= ifind[1];
    __syncthreads();
  }
  if (t == 0) cnt_sh = 0;
  __syncthreads();
  for (int i = t; i < NN; i += 256) {
    if (keys[i] >= theta) {
      int p = atomicAdd(&cnt_sh, 1);
      idxl[p] = 4095 - (int)(keys[i] & 0xFFFull);  // order irrelevant for loss
    }
  }
  __syncthreads();

  // ---------- Phase B: gather point + row softmax stats (thread t = row k)
  const int myi = idxl[t];
  const float* xr = pts + ((size_t)b * NN + myi) * 3;
  const float px = xr[0], py = xr[1], pz = xr[2];
  x4[4 * t] = px; x4[4 * t + 1] = py; x4[4 * t + 2] = pz; x4[4 * t + 3] = 0.f;
  const float* lr = lg + ((size_t)b * NN + myi) * NJ;
  float m = -3.4e38f;
#pragma unroll 4
  for (int j = 0; j < NJ; j += 4) {
    float4 v = *(const float4*)(lr + j);
    m = fmaxf(m, fmaxf(fmaxf(v.x, v.y), fmaxf(v.z, v.w)));
  }
  float zz = 0.f;
#pragma unroll 4
  for (int j = 0; j < NJ; j += 4) {
    float4 v = *(const float4*)(lr + j);
    zz += __expf(v.x - m) + __expf(v.y - m) + __expf(v.z - m) + __expf(v.w - m);
  }
  const float myck = m + __logf(zz);  // logsumexp of row
  ckv[t] = myck;
  __syncthreads();

  // ---------- Phase C: pi_j, mu_j (thread t = column j)
  {
    const float* lgb = lg + (size_t)b * NN * NJ;
    float pi = 0.f, a0 = 0.f, a1 = 0.f, a2 = 0.f;
#pragma unroll 4
    for (int k = 0; k < NK; ++k) {
      float lv = lgb[(size_t)idxl[k] * NJ + t];
      float S = __expf(lv - ckv[k]);  // softmax entry
      float4 xx = *(const float4*)&x4[4 * k];
      pi += S;
      a0 = fmaf(S, xx.x, a0); a1 = fmaf(S, xx.y, a1); a2 = fmaf(S, xx.z, a2);
    }
    float pim = fmaxf(pi * (1.f / 256.f), 1e-4f);  // clip(mean, 1e-4)
    float npi = pim * 256.f;
    float m0 = a0 / npi, m1 = a1 / npi, m2 = a2 / npi;
    mu4[4 * t] = m0; mu4[4 * t + 1] = m1; mu4[4 * t + 2] = m2;
    // w_j = -10*log2(e)*|mu_j|^2
    mu4[4 * t + 3] = -14.426950408889634f * (m0 * m0 + m1 * m1 + m2 * m2);
    float ssum = wredf(pim);
    if (lane == 0) redf4[wid] = ssum;
    __syncthreads();
    float tot = redf4[0] + redf4[1] + redf4[2] + redf4[3];
    cjv[t] = fmaxf(pim / tot, 1e-9f);  // log_c = log(clip(p/sum p, 1e-9))
  }
  __syncthreads();

  // ---------- Phase D: K~ row (row-max-shifted kernel), thread t = row k
  // log2 K = -10*log2e*(|x|^2+|mu|^2-2 x.mu); |x|^2 term cancels in rowmax shift
  {
    const float xp0 = px * 28.853900817779268f;   // 20*log2(e)*x
    const float xp1 = py * 28.853900817779268f;
    const float xp2 = pz * 28.853900817779268f;
    float rm = -3.4e38f;
#pragma unroll 4
    for (int j = 0; j < NJ; ++j) {
      float4 mm = *(const float4*)&mu4[4 * j];
      float sj = fmaf(xp0, mm.x, fmaf(xp1, mm.y, fmaf(xp2, mm.z, mm.w)));
      rm = fmaxf(rm, sj);
    }
    float* krow = kw + (((size_t)b << 16) + ((size_t)t << 8));
#pragma unroll 2
    for (int j = 0; j < NJ; j += 4) {
      float4 mm0 = *(const float4*)&mu4[4 * j];
      float4 mm1 = *(const float4*)&mu4[4 * (j + 1)];
      float4 mm2 = *(const float4*)&mu4[4 * (j + 2)];
      float4 mm3 = *(const float4*)&mu4[4 * (j + 3)];
      float4 o;
      o.x = exp2f(fmaf(xp0, mm0.x, fmaf(xp1, mm0.y, fmaf(xp2, mm0.z, mm0.w))) - rm);
      o.y = exp2f(fmaf(xp0, mm1.x, fmaf(xp1, mm1.y, fmaf(xp2, mm1.z, mm1.w))) - rm);
      o.z = exp2f(fmaf(xp0, mm2.x, fmaf(xp1, mm2.y, fmaf(xp2, mm2.z, mm2.w))) - rm);
      o.w = exp2f(fmaf(xp0, mm3.x, fmaf(xp1, mm3.y, fmaf(xp2, mm3.z, mm3.w))) - rm);
      *(float4*)(krow + j) = o;
    }
    bv[t] = 1.f;  // log_v = 0 init
  }
  __syncthreads();

  // ---------- Phase E: 25 primal Sinkhorn iterations (u-update then v-update)
  const float* kbase = kw + ((size_t)b << 16);
  const float4* kr4 = (const float4*)(kbase + ((size_t)t << 8));
  const float4* bv4 = (const float4*)bv;
#pragma unroll 1
  for (int it = 0; it < NITER; ++it) {
    float acc = 0.f;  // (K~ b)_k, thread t = row k
#pragma unroll 8
    for (int j4 = 0; j4 < 64; ++j4) {
      float4 kv = kr4[j4];
      float4 b4 = bv4[j4];
      acc = fmaf(kv.x, b4.x, fmaf(kv.y, b4.y, fmaf(kv.z, b4.z, fmaf(kv.w, b4.w, acc))));
    }
    av[t] = (1.f / 256.f) / fmaxf(acc, 1e-35f);
    __syncthreads();
    float acc2 = 0.f;  // (K~^T a)_j, thread t = col j
    const float* kc = kbase + t;
#pragma unroll 16
    for (int k = 0; k < NK; ++k) acc2 = fmaf(kc[(size_t)k << 8], av[k], acc2);
    bv[t] = cjv[t] / fmaxf(acc2, 1e-35f);
    __syncthreads();
  }

  // ---------- Phase F: loss_k = (a_k/denom_k) * sum_j K~ b_j (ck - lg)
  {
    float rs = 0.f;
#pragma unroll 8
    for (int j4 = 0; j4 < 64; ++j4) {
      float4 kv = kr4[j4];
      float4 b4 = bv4[j4];
      rs = fmaf(kv.x, b4.x, fmaf(kv.y, b4.y, fmaf(kv.z, b4.z, fmaf(kv.w, b4.w, rs))));
    }
    const float atk = av[t];
    const float fko = atk / fmaxf(atk * rs, 1e-4f);  // clip(rowsum T, 1e-4)
    const float* lr2 = lg + ((size_t)b * NN + myi) * NJ;
    float acc = 0.f;
#pragma unroll 4
    for (int j4 = 0; j4 < 64; ++j4) {
      float4 kv = kr4[j4];
      float4 b4 = bv4[j4];
      float4 l4 = *(const float4*)(lr2 + 4 * j4);
      acc = fmaf(kv.x * b4.x, myck - l4.x, acc);
      acc = fmaf(kv.y * b4.y, myck - l4.y, acc);
      acc = fmaf(kv.z * b4.z, myck - l4.z, acc);
      acc = fmaf(kv.w * b4.w, myck - l4.w, acc);
    }
    float lk = fko * acc;
    float s2 = wredf(lk);
    if (lane == 0) redf4[wid] = s2;
    __syncthreads();
    if (t == 0) bloss[b] = redf4[0] + redf4[1] + redf4[2] + redf4[3];
  }
}

__global__ __launch_bounds__(128) void km_fin(const float* __restrict__ bloss,
                                              float* __restrict__ out) {
  int t = threadIdx.x;
  float v = bloss[t];
  v = wredf(v);
  __shared__ float r2[2];
  if ((t & 63) == 0) r2[t >> 6] = v;
  __syncthreads();
  if (t == 0) out[0] = (r2[0] + r2[1]) * (1.f / 32768.f);  // mean over B*J
}

extern "C" void kernel_launch(void* const* d_in, const int* in_sizes, int n_in,
                              void* d_out, int out_size, void* d_ws, size_t ws_size,
                              hipStream_t stream) {
  const float* pts = (const float*)d_in[0];
  const float* lg = (const float*)d_in[1];
  const float* prob = (const float*)d_in[2];
  float* kw = (float*)d_ws;                                   // 128*65536 f32 = 32 MB
  float* bloss = (float*)((char*)d_ws + (size_t)NB * 65536 * 4);
  km_main<<<NB, 256, 0, stream>>>(pts, lg, prob, kw, bloss);
  km_fin<<<1, 128, 0, stream>>>(bloss, (float*)d_out);
}

// Round 5
// 841.077 us; speedup vs baseline: 1.1653x; 1.1653x over previous
//
#include <hip/hip_runtime.h>
#include <stdint.h>

#define NB 128
#define NN 4096
#define NJ 256
#define NK 256
#define NITER 25
#define PAD 68

__device__ __forceinline__ float wredf(float v) {
#pragma unroll
  for (int o = 32; o > 0; o >>= 1) v += __shfl_xor(v, o, 64);
  return v;
}
__device__ __forceinline__ float qsum(float v) {
  v += __shfl_xor(v, 1, 64);
  v += __shfl_xor(v, 2, 64);
  return v;
}
__device__ __forceinline__ float qmax(float v) {
  v = fmaxf(v, __shfl_xor(v, 1, 64));
  v = fmaxf(v, __shfl_xor(v, 2, 64));
  return v;
}

// One block per batch, 1024 threads (16 waves/CU).
// Quad map: kj = t>>2 (row in B/D/E-row/F-row, column in C/E-col/F-col), q = t&3 (quarter).
__global__ __launch_bounds__(1024) void km_main(
    const float* __restrict__ pts, const float* __restrict__ lg,
    const float* __restrict__ prob, float* __restrict__ kw,
    float* __restrict__ bloss) {
  const int b = blockIdx.x;
  const int t = threadIdx.x;
  const int lane = t & 63, w = t >> 6;
  const int kj = t >> 2, q = t & 3;

  __shared__ __align__(16) int pool[4096];  // 16 KB: hist in Phase A, small arrays after
  __shared__ int warr[16];
  __shared__ float warf[16];
  __shared__ int ifind[2];
  __shared__ int cnt_sh;

  int* hist = pool;
  // post-Phase-A overlays (all offsets 16B-aligned where float4-read):
  int(*idxp)[PAD] = (int(*)[PAD])pool;                        // 1088 B @ 0
  float(*ckvp)[PAD] = (float(*)[PAD])((char*)pool + 1088);    // 1088 B
  float(*avp)[PAD] = (float(*)[PAD])((char*)pool + 2176);     // 1088 B (float4-read)
  float(*bvp)[PAD] = (float(*)[PAD])((char*)pool + 3264);     // 1088 B (float4-read)
  float4(*x4p)[65] = (float4(*)[65])((char*)pool + 4352);     // 4160 B
  float4(*mup)[65] = (float4(*)[65])((char*)pool + 8512);     // 4160 B
  float(*fgp)[136] = (float(*)[136])((char*)pool + 12672);    // 2176 B (float2-read)
  float* cjv = (float*)((char*)pool + 14848);                 // 1024 B -> 15872 total

  // ---------- Phase A: exact top-256 (ties -> lower index), radix select.
  // prob values cached in 4 registers; 44-bit key recomputed on the fly.
  const float* pb = prob + (size_t)b * NN;
  unsigned pbits[4];
#pragma unroll
  for (int r = 0; r < 4; ++r) pbits[r] = __float_as_uint(pb[t + 1024 * r]);

  unsigned long long theta = 0ull;
  int need = NK;
  const int shv[4] = {32, 20, 8, 0};
  const int psv[4] = {44, 32, 20, 8};
#pragma unroll 1
  for (int L = 0; L < 4; ++L) {
    const int sh = shv[L], ps = psv[L];
    for (int i = t; i < 4096; i += 1024) hist[i] = 0;
    __syncthreads();
#pragma unroll
    for (int r = 0; r < 4; ++r) {
      int i = t + 1024 * r;
      unsigned long long kk =
          ((unsigned long long)pbits[r] << 12) | (unsigned)(4095 - i);
      if ((kk >> ps) == (theta >> ps))
        atomicAdd(&hist[(int)((kk >> sh) & 0xFFFull)], 1);
    }
    __syncthreads();
    int loc[4];
    int tot = 0;
#pragma unroll
    for (int qq = 3; qq >= 0; --qq) { loc[qq] = tot; tot += hist[4 * t + qq]; }
    int s = tot;  // inclusive suffix over lanes (higher lanes own higher bins)
#pragma unroll
    for (int o = 1; o < 64; o <<= 1) {
      int u = __shfl_down(s, o, 64);
      if (lane + o < 64) s += u;
    }
    if (lane == 0) warr[w] = s;
    __syncthreads();
    int gtw = s - tot;
    for (int w2 = w + 1; w2 < 16; ++w2) gtw += warr[w2];
#pragma unroll
    for (int qq = 0; qq < 4; ++qq) {
      int g = gtw + loc[qq];
      int h = hist[4 * t + qq];
      if (g < need && g + h >= need) { ifind[0] = 4 * t + qq; ifind[1] = g; }
    }
    __syncthreads();
    theta |= ((unsigned long long)ifind[0]) << sh;
    need -= ifind[1];
  }
  if (t == 0) cnt_sh = 0;
  __syncthreads();
#pragma unroll
  for (int r = 0; r < 4; ++r) {
    int i = t + 1024 * r;
    unsigned long long kk =
        ((unsigned long long)pbits[r] << 12) | (unsigned)(4095 - i);
    if (kk >= theta) {
      int p = atomicAdd(&cnt_sh, 1);
      idxp[p >> 6][p & 63] = i;  // order irrelevant for the loss
    }
  }
  __syncthreads();

  // ---------- Phase B: gather point + row logsumexp (row kj, quarter q)
  const int myi = idxp[kj >> 6][kj & 63];
  const float* xr = pts + ((size_t)b * NN + myi) * 3;
  const float px = xr[0], py = xr[1], pz = xr[2];
  if (q == 0) x4p[kj >> 6][kj & 63] = make_float4(px, py, pz, 0.f);
  const float4* lr4 = (const float4*)(lg + ((size_t)b * NN + myi) * NJ + q * 64);
  float lvv[64];
  float rmB = -3.4e38f;
#pragma unroll
  for (int m4 = 0; m4 < 16; ++m4) {
    float4 v = lr4[m4];
    lvv[4 * m4] = v.x; lvv[4 * m4 + 1] = v.y;
    lvv[4 * m4 + 2] = v.z; lvv[4 * m4 + 3] = v.w;
    rmB = fmaxf(rmB, fmaxf(fmaxf(v.x, v.y), fmaxf(v.z, v.w)));
  }
  rmB = qmax(rmB);
  float zz = 0.f;
#pragma unroll
  for (int m = 0; m < 64; ++m) zz += __expf(lvv[m] - rmB);
  zz = qsum(zz);
  const float myck = rmB + __logf(zz);  // row logsumexp (all quad lanes)
  if (q == 0) ckvp[kj >> 6][kj & 63] = myck;
  __syncthreads();

  // ---------- Phase C: pi_j, mu_j (column kj, k-quarter q)
  const float* lgb = lg + (size_t)b * NN * NJ;
  {
    float pi = 0.f, a0 = 0.f, a1 = 0.f, a2 = 0.f;
#pragma unroll 8
    for (int n = 0; n < 64; ++n) {
      int kk2 = idxp[q][n];
      float lv = lgb[(size_t)kk2 * NJ + kj];  // coalesced over lanes
      float S = __expf(lv - ckvp[q][n]);
      float4 xx = x4p[q][n];
      pi += S;
      a0 = fmaf(S, xx.x, a0); a1 = fmaf(S, xx.y, a1); a2 = fmaf(S, xx.z, a2);
    }
    pi = qsum(pi); a0 = qsum(a0); a1 = qsum(a1); a2 = qsum(a2);
    float pim = fmaxf(pi * (1.f / 256.f), 1e-4f);  // clip(mean, 1e-4)
    float npi = pim * 256.f;
    float m0 = a0 / npi, m1 = a1 / npi, m2 = a2 / npi;
    if (q == 0)
      mup[kj >> 6][kj & 63] = make_float4(
          m0, m1, m2, -14.426950408889634f * (m0 * m0 + m1 * m1 + m2 * m2));
    float cc = (q == 0) ? pim : 0.f;
    cc = wredf(cc);
    if (lane == 0) warf[w] = cc;
    __syncthreads();
    float totp = 0.f;
#pragma unroll
    for (int i = 0; i < 16; ++i) totp += warf[i];
    if (q == 0) cjv[kj] = fmaxf(pim / totp, 1e-9f);
  }

  // ---------- Phase D: K~ quarter-row into registers + row-major global copy
  // log2 K = -10*log2e*cost; |x|^2 cancels in the row-max shift.
  float kreg[64];
  {
    const float xp0 = px * 28.853900817779268f;  // 20*log2(e)*x
    const float xp1 = py * 28.853900817779268f;
    const float xp2 = pz * 28.853900817779268f;
    float rm = -3.4e38f;
#pragma unroll
    for (int m = 0; m < 64; ++m) {
      float4 mm = mup[q][m];
      float sv = fmaf(xp0, mm.x, fmaf(xp1, mm.y, fmaf(xp2, mm.z, mm.w)));
      kreg[m] = sv;
      rm = fmaxf(rm, sv);
    }
    rm = qmax(rm);  // full-row max across the quad
#pragma unroll
    for (int m = 0; m < 64; ++m) kreg[m] = exp2f(kreg[m] - rm);
    float4* kst4 = (float4*)(kw + ((size_t)b << 16) + (size_t)kj * 256 + q * 64);
#pragma unroll
    for (int m4 = 0; m4 < 16; ++m4)
      kst4[m4] = make_float4(kreg[4 * m4], kreg[4 * m4 + 1], kreg[4 * m4 + 2],
                             kreg[4 * m4 + 3]);
    if (t < 256) bvp[t >> 6][t & 63] = 1.f;  // log_v = 0 init
  }
  __syncthreads();

  // ---------- Phase E: 25 primal Sinkhorn iterations
  // row pass: registers only; col pass: coalesced L2 reads of row-major K~.
  const float* kcb = kw + ((size_t)b << 16) + (size_t)(q * 64) * 256 + kj;
  const float4* bq4 = (const float4*)(&bvp[q][0]);
  const float4* aq4 = (const float4*)(&avp[q][0]);
  float aval = 0.f;
#pragma unroll 1
  for (int it = 0; it < NITER; ++it) {
    float r0 = 0.f, r1 = 0.f, r2 = 0.f, r3 = 0.f;
#pragma unroll
    for (int m4 = 0; m4 < 16; ++m4) {
      float4 bb = bq4[m4];
      r0 = fmaf(kreg[4 * m4], bb.x, r0);
      r1 = fmaf(kreg[4 * m4 + 1], bb.y, r1);
      r2 = fmaf(kreg[4 * m4 + 2], bb.z, r2);
      r3 = fmaf(kreg[4 * m4 + 3], bb.w, r3);
    }
    float acc = qsum((r0 + r1) + (r2 + r3));  // (K~ b)_k
    aval = (1.f / 256.f) / fmaxf(acc, 1e-35f);
    if (q == 0) avp[kj >> 6][kj & 63] = aval;
    __syncthreads();
    float c0 = 0.f, c1 = 0.f;
#pragma unroll 8
    for (int n4 = 0; n4 < 16; ++n4) {
      float4 a4 = aq4[n4];
      c0 = fmaf(kcb[(size_t)(4 * n4) * 256], a4.x, c0);
      c1 = fmaf(kcb[(size_t)(4 * n4 + 1) * 256], a4.y, c1);
      c0 = fmaf(kcb[(size_t)(4 * n4 + 2) * 256], a4.z, c0);
      c1 = fmaf(kcb[(size_t)(4 * n4 + 3) * 256], a4.w, c1);
    }
    float acc2 = qsum(c0 + c1);  // (K~^T a)_j
    float bnew = cjv[kj] / fmaxf(acc2, 1e-35f);
    if (q == 0) bvp[kj >> 6][kj & 63] = bnew;
    __syncthreads();
  }

  // ---------- Phase F: loss, column formulation
  {
    // final row pass (registers): rowsum(T)_k = a_k * (K~ b)_k
    float r0 = 0.f, r1 = 0.f, r2 = 0.f, r3 = 0.f;
#pragma unroll
    for (int m4 = 0; m4 < 16; ++m4) {
      float4 bb = bq4[m4];
      r0 = fmaf(kreg[4 * m4], bb.x, r0);
      r1 = fmaf(kreg[4 * m4 + 1], bb.y, r1);
      r2 = fmaf(kreg[4 * m4 + 2], bb.z, r2);
      r3 = fmaf(kreg[4 * m4 + 3], bb.w, r3);
    }
    float rs = qsum((r0 + r1) + (r2 + r3));
    float fko = aval / fmaxf(aval * rs, 1e-4f);  // a_k / clip(rowsum T, 1e-4)
    if (q == 0) {
      fgp[kj >> 6][2 * (kj & 63)] = fko;
      fgp[kj >> 6][2 * (kj & 63) + 1] = fko * myck;
    }
    __syncthreads();
    float bj = bvp[kj >> 6][kj & 63];
    const float2* fg2 = (const float2*)(&fgp[q][0]);
    float la = 0.f, lb2 = 0.f;
#pragma unroll 4
    for (int n = 0; n < 64; ++n) {
      float Kv = kcb[(size_t)n * 256];            // coalesced
      int kk2 = idxp[q][n];
      float lgv = lgb[(size_t)kk2 * NJ + kj];     // coalesced
      float2 fg = fg2[n];                         // {fko_k, fko_k*ck_k}
      la = fmaf(Kv, fg.y, la);
      lb2 = fmaf(Kv * fg.x, lgv, lb2);
    }
    float accF = qsum(la - lb2);
    float v = (q == 0) ? bj * accF : 0.f;  // loss_j = b_j * sum_k K~*(g - fko*lg)
    v = wredf(v);
    if (lane == 0) warf[w] = v;
    __syncthreads();
    if (t == 0) {
      float sv = 0.f;
#pragma unroll
      for (int i = 0; i < 16; ++i) sv += warf[i];
      bloss[b] = sv;
    }
  }
}

__global__ __launch_bounds__(128) void km_fin(const float* __restrict__ bloss,
                                              float* __restrict__ out) {
  int t = threadIdx.x;
  float v = bloss[t];
  v = wredf(v);
  __shared__ float r2[2];
  if ((t & 63) == 0) r2[t >> 6] = v;
  __syncthreads();
  if (t == 0) out[0] = (r2[0] + r2[1]) * (1.f / 32768.f);  // mean over B*J
}

extern "C" void kernel_launch(void* const* d_in, const int* in_sizes, int n_in,
                              void* d_out, int out_size, void* d_ws, size_t ws_size,
                              hipStream_t stream) {
  const float* pts = (const float*)d_in[0];
  const float* lg = (const float*)d_in[1];
  const float* prob = (const float*)d_in[2];
  float* kw = (float*)d_ws;  // 128 * 65536 f32 = 32 MB
  float* bloss = (float*)((char*)d_ws + (size_t)NB * 65536 * 4);
  km_main<<<NB, 1024, 0, stream>>>(pts, lg, prob, kw, bloss);
  km_fin<<<1, 128, 0, stream>>>(bloss, (float*)d_out);
}